// Round 1
// baseline (463.483 us; speedup 1.0000x reference)
//
#include <hip/hip_runtime.h>

#define CROP 14
#define MAXBS 64
#define NLVL 4
#define BDIM 4
#define NBOX 128
#define CCH 256

// Kernel A: per-batch rank scan -> slot_map + output1.
// grid = B (4), block = 256 (one thread per (lvl,slot) pair).
__global__ void roi_meta_kernel(const float* __restrict__ db,
                                int* __restrict__ slot_map,
                                float* __restrict__ out1) {
    int b = blockIdx.x;
    int t = threadIdx.x;            // 0..255 = lvl*64 + slot
    __shared__ int lvl_arr[NBOX];
    __shared__ int smap[NLVL * MAXBS];

    if (t < NBOX) {
        // ids are exact small floats 0.0..3.0
        lvl_arr[t] = (int)db[(b * NBOX + t) * 7 + 0];
    }
    smap[t] = -1;
    __syncthreads();

    if (t < NLVL) {
        int r = 0;
        for (int n = 0; n < NBOX; ++n) {
            if (lvl_arr[n] == t) {
                if (r < MAXBS) smap[t * MAXBS + r] = n;
                r++;  // rank keeps counting; >=64 dropped (dest==MAX_BS slot)
            }
        }
    }
    __syncthreads();

    int n = smap[t];
    int lvl = t >> 6;
    int slot = t & 63;
    slot_map[(lvl * BDIM + b) * MAXBS + slot] = n;

    // output1: [B, NLVL*MAXBS, 6], level-concatenated along axis 1
    float* o = out1 + ((size_t)(b * (NLVL * MAXBS) + t)) * 6;
    if (n >= 0) {
        const float* src = db + (b * NBOX + n) * 7 + 1;  // cx,cy,w,h,cls,conf
        #pragma unroll
        for (int j = 0; j < 6; ++j) o[j] = src[j];
    } else {
        #pragma unroll
        for (int j = 0; j < 6; ++j) o[j] = 0.f;
    }
}

// Kernel B: one block per (lvl,b,slot,y) output row; thread = channel.
// grid = NLVL*BDIM*MAXBS*CROP = 14336, block = 256.
__global__ void roi_crop_kernel(const float* __restrict__ f0,
                                const float* __restrict__ f1,
                                const float* __restrict__ f2,
                                const float* __restrict__ f3,
                                const float* __restrict__ db,
                                const int* __restrict__ slot_map,
                                float* __restrict__ out0) {
    int bid = blockIdx.x;
    int y  = bid % CROP;
    int sl = bid / CROP;            // lvl*256 + b*64 + slot, 0..1023
    int c  = threadIdx.x;           // channel 0..255

    float* out = out0 + ((size_t)(sl * CROP + y)) * CROP * CCH;

    int n = slot_map[sl];
    if (n < 0) {
        #pragma unroll
        for (int x = 0; x < CROP; ++x) out[x * CCH + c] = 0.f;
        return;
    }

    int lvl = sl >> 8;
    int b   = (sl >> 6) & 3;
    int s   = 256 >> lvl;           // fmap H == W
    const float* f = (lvl == 0) ? f0 : (lvl == 1) ? f1 : (lvl == 2) ? f2 : f3;

    const float* bx = db + (b * NBOX + n) * 7;
    float cx = bx[1], cy = bx[2], w = bx[3], h = bx[4];

    // normalized box, matching reference fp32 op order
    float y1n = (cy - h * 0.5f) / 1023.0f;
    float x1n = (cx - w * 0.5f) / 1023.0f;
    float y2n = (cy + h * 0.5f) / 1023.0f;
    float x2n = (cx + w * 0.5f) / 1023.0f;

    float Hm1 = (float)(s - 1);
    float ty = (float)y / 13.0f;
    float ys = y1n * Hm1 + ty * ((y2n - y1n) * Hm1);
    float y0f = floorf(ys);
    float wy = ys - y0f;
    int iy0 = (int)y0f;
    iy0 = iy0 < 0 ? 0 : (iy0 > s - 1 ? s - 1 : iy0);
    int iy1 = iy0 + 1;
    if (iy1 > s - 1) iy1 = s - 1;
    bool vy = (ys >= 0.f) && (ys <= Hm1);

    const float* rowT = f + ((size_t)(b * s + iy0)) * s * CCH;
    const float* rowB = f + ((size_t)(b * s + iy1)) * s * CCH;

    float x1nH   = x1n * Hm1;
    float xscale = (x2n - x1n) * Hm1;
    float omwy = 1.f - wy;

    #pragma unroll
    for (int x = 0; x < CROP; ++x) {
        float xs = x1nH + ((float)x / 13.0f) * xscale;
        float x0f = floorf(xs);
        float wx = xs - x0f;
        int ix0 = (int)x0f;
        ix0 = ix0 < 0 ? 0 : (ix0 > s - 1 ? s - 1 : ix0);
        int ix1 = ix0 + 1;
        if (ix1 > s - 1) ix1 = s - 1;
        bool vx = (xs >= 0.f) && (xs <= Hm1);

        float a  = rowT[ix0 * CCH + c];
        float bv = rowT[ix1 * CCH + c];
        float cv = rowB[ix0 * CCH + c];
        float dv = rowB[ix1 * CCH + c];

        float omwx = 1.f - wx;
        float top = a  * omwx + bv * wx;
        float bot = cv * omwx + dv * wx;
        float v   = top * omwy + bot * wy;

        out[x * CCH + c] = (vy && vx) ? v : 0.f;
    }
}

extern "C" void kernel_launch(void* const* d_in, const int* in_sizes, int n_in,
                              void* d_out, int out_size, void* d_ws, size_t ws_size,
                              hipStream_t stream) {
    const float* f0 = (const float*)d_in[0];
    const float* f1 = (const float*)d_in[1];
    const float* f2 = (const float*)d_in[2];
    const float* f3 = (const float*)d_in[3];
    const float* db = (const float*)d_in[4];
    // d_in[5] = images, only shapes (1024x1024) are used -> hardcoded

    float* out0 = (float*)d_out;
    float* out1 = out0 + (size_t)NLVL * BDIM * MAXBS * CROP * CROP * CCH;
    int* slot_map = (int*)d_ws;     // 4 KB

    roi_meta_kernel<<<BDIM, 256, 0, stream>>>(db, slot_map, out1);
    roi_crop_kernel<<<NLVL * BDIM * MAXBS * CROP, 256, 0, stream>>>(
        f0, f1, f2, f3, db, slot_map, out0);
}